// Round 4
// 12645.356 us; speedup vs baseline: 1.2320x; 1.2320x over previous
//
#include <hip/hip_runtime.h>
#include <hip/hip_bf16.h>
#include <cmath>

typedef __bf16 bf16_t;
typedef unsigned short u16;
typedef unsigned int u32;
typedef float f32x4 __attribute__((ext_vector_type(4)));
typedef short s16x8 __attribute__((ext_vector_type(8)));
typedef u32   u32x4 __attribute__((ext_vector_type(4)));
#define DEVINL __device__ __forceinline__
#define POSTN 300

// ---- workspace layout (bytes). NEED = 52,176,516 ---- (round-0 layout, verified)
#define XPT_OFF  0ull           // [8 img][512 ci][18*81] f32 = 23,887,872  (padded t,h,w)
#define YT_OFF   23887872ull    // [8 img][512 co][16*81] f32 = 21,233,664  (padded h,w)
#define F_OFF    45121536ull    // [1568][512] f32 = 3,211,264
#define PART_OFF 48332800ull    // [4][392][512] f32 = 3,211,264
#define SC_OFF   51544064ull    // [32*441] f32
#define BX_OFF   51600512ull    // [32*441*4] f32
#define K1_OFF   51826304ull    // [13824] int
#define K2_OFF   51881600ull    // [73728] int
#define FLAG_OFF 52176512ull
#define NEED     52176516ull

// dtype-branched float load (flag: 1 = inputs are f32, 0 = bf16)
DEVINL float ldf(const void* p, long i, int f32m) {
  return f32m ? ((const float*)p)[i] : (float)(((const bf16_t*)p)[i]);
}

// NaN-safe clamp (NaN -> lo), not foldable to bare v_med3
DEVINL float clampf(float v, float lo, float hi) {
  if (!(v == v)) return lo;
  if (v < lo) return lo;
  if (v > hi) return hi;
  return v;
}

DEVINL u16 b16u(float v) {
  bf16_t h = (bf16_t)v;
  u16 r;
  __builtin_memcpy(&r, &h, 2);
  return r;
}

// ---------- input dtype detector ----------
__global__ __launch_bounds__(256) void detect_dtype(const void* bf, const void* w1, int* flag) {
  __shared__ int cnt;
  int tid = threadIdx.x;
  if (tid == 0) cnt = 0;
  __syncthreads();
  // even-indexed bf16 decodes are garbage iff underlying data is f32 (low mantissa bits)
  float a = (float)(((const bf16_t*)bf)[2 * tid]);
  float b = (float)(((const bf16_t*)w1)[2 * tid]);
  int wc = 0;
  if (!(a == a) || fabsf(a) > 1e20f || (a != 0.f && fabsf(a) < 1e-20f)) wc++;
  if (!(b == b) || fabsf(b) > 1e20f || (b != 0.f && fabsf(b) < 1e-20f)) wc++;
  atomicAdd(&cnt, wc);
  __syncthreads();
  if (tid == 0) *flag = (cnt >= 16) ? 1 : 0;
}

// ---------- k -> activation-offset tables ----------
__global__ __launch_bounds__(256) void build_koff(int* k1, int* k2) {
  int i = blockIdx.x * 256 + threadIdx.x;
  if (i < 13824) {               // k = ci*27 + tap ; XpT ci-stride 1458
    int ci = i / 27, tap = i % 27;
    k1[i] = ci * 1458 + (tap / 9) * 81 + ((tap % 9) / 3) * 9 + (tap % 3);
  }
  if (i < 73728) {               // k = ci*144 + tap ; Yt ci-stride 1296
    int ci = i / 144, tap = i % 144;
    k2[i] = ci * 1296 + (tap / 9) * 81 + ((tap % 9) / 3) * 9 + (tap % 3);
  }
}

// ---------- pad-only copy: X[b][ci][t][h][w] -> XpT[b][ci][t+1][h+1][w+1] (f32) ----------
__global__ __launch_bounds__(256) void pad_x(const void* __restrict__ X, float* __restrict__ XpT,
                                             const int* __restrict__ flagp, int cb) {
  int f32m = *flagp;
  long e = (long)blockIdx.x * 256 + threadIdx.x;      // < 8*512*784
  if (e >= 8L * 512 * 784) return;
  int f = (int)(e % 784);
  long bc = e / 784;                                   // local_b*512 + ci
  int t = f / 49, h = (f % 49) / 7, w = f % 7;
  float v = ldf(X, ((long)cb * 512 * 784) + bc * 784 + f, f32m);
  XpT[bc * 1458 + (t + 1) * 81 + (h + 1) * 9 + (w + 1)] = v;
}

// ---------- f32 tiled GEMM (64x64 tile, 4x4 per thread), implicit conv (round-0, verified) ----
// MODE 1: conv1 chunk (f32-input mode ONLY; bf16 mode handled by gemm_mf1).
// MODE 2: conv2 chunk. A[m=(b,h,w)][k=(ci,tap144)] from Yt; B = w2 rows; split-K=4.
template <int MODE>
__global__ __launch_bounds__(256) void gemm_f32(
    const float* __restrict__ Act, const void* __restrict__ Wgt, const void* __restrict__ bias,
    float* __restrict__ Yt, float* __restrict__ Part,
    const int* __restrict__ koff, const int* __restrict__ flagp) {
  const int f32m = *flagp;
  if (MODE == 1 && f32m == 0) return;     // MFMA path owns conv1 in bf16 mode
  const int tid = threadIdx.x;
  int mt, nt, s = 0;
  if (MODE == 1) { mt = blockIdx.x % 98; nt = blockIdx.x / 98; }
  else           { mt = blockIdx.x % 7;  nt = (blockIdx.x / 7) % 8; s = blockIdx.x / 56; }
  const int m0 = mt * 64, n0 = nt * 64;
  const int K     = (MODE == 1) ? 13824 : 18432;     // k-extent (per split for MODE 2)
  const int kBase = (MODE == 1) ? 0     : s * 18432;
  const int WROW  = (MODE == 1) ? 13824 : 73728;

  __shared__ __align__(16) float As[64][68];   // [k][m], +4 pad
  __shared__ __align__(16) float Bs[64][68];   // [k][n]

  const int am = tid & 63, akq = tid >> 6;
  long aBase;
  {
    int m = m0 + am;
    if (MODE == 1) {
      int b = m / 784, r = m % 784, t = r / 49, h = (r % 49) / 7, w = r % 7;
      aBase = (long)b * (512 * 1458) + t * 81 + h * 9 + w;
    } else {
      if (m > 391) m = 391;
      int b = m / 49, r = m % 49, h = r / 7, w = r % 7;
      aBase = (long)b * (512 * 1296) + h * 9 + w;
    }
  }
  const int bn = tid >> 2, bks = (tid & 3) * 16;
  const long bBase = (long)(n0 + bn) * WROW + kBase;

  float acc[4][4] = {{0.f}};
  const int tx = tid & 15, ty = tid >> 4;

  for (int k0 = 0; k0 < K; k0 += 64) {
    __syncthreads();
#pragma unroll
    for (int j = 0; j < 16; j++) {
      int kk = akq * 16 + j;
      As[kk][am] = Act[aBase + koff[kBase + k0 + kk]];
    }
#pragma unroll
    for (int j = 0; j < 16; j++) {
      int kk = bks + j;
      Bs[kk][bn] = ldf(Wgt, bBase + k0 + kk, f32m);
    }
    __syncthreads();
#pragma unroll 8
    for (int k = 0; k < 64; k++) {
      f32x4 a = *(const f32x4*)&As[k][tx * 4];
      f32x4 b = *(const f32x4*)&Bs[k][ty * 4];
#pragma unroll
      for (int i = 0; i < 4; i++)
#pragma unroll
        for (int j = 0; j < 4; j++) acc[i][j] += a[i] * b[j];
    }
  }

#pragma unroll
  for (int i = 0; i < 4; i++) {
    int m = m0 + tx * 4 + i;
#pragma unroll
    for (int j = 0; j < 4; j++) {
      int n = n0 + ty * 4 + j;
      if (MODE == 1) {
        int b = m / 784, r = m % 784, t = r / 49, h = (r % 49) / 7, w = r % 7;
        float v = acc[i][j] + ldf(bias, n, f32m);
        v = fmaxf(v, 0.f);
        Yt[(long)(b * 512 + n) * 1296 + t * 81 + (h + 1) * 9 + (w + 1)] = v;
      } else {
        if (m < 392) Part[((long)s * 392 + m) * 512 + n] = acc[i][j];
      }
    }
  }
}

// ---------- MFMA conv1 (bf16 input mode only; exact products, f32 accumulation) ----------
// A[m=(b,t,h,w)][k] gathered from f32 XpT (values exactly bf16), cast to bf16.
// B = w1 rows (native bf16). Block tile 128x64, BK=64, 4 waves,
// wave 64x32 = 4x2 frags of mfma_f32_16x16x32_bf16. XOR-swizzled LDS (k-block ^ row&7).
__global__ __launch_bounds__(256) void gemm_mf1(
    const float* __restrict__ Act, const void* __restrict__ Wgt, const void* __restrict__ bias,
    float* __restrict__ Yt, const int* __restrict__ koff, const int* __restrict__ flagp) {
  if (*flagp != 0) return;            // f32-input mode handled by gemm_f32<1>
  const int tid = threadIdx.x;
  const int mt = blockIdx.x % 49, nt = blockIdx.x / 49;   // 392 blocks, M=6272 exact
  const int m0 = mt * 128, n0 = nt * 64;

  __shared__ u16 As[128 * 64];
  __shared__ u16 Bs[64 * 64];

  // staging ids: A (each of 256 threads stages one row-half: 32 k gathers)
  const int am = tid & 127, khu = tid >> 7;
  long aBase;
  {
    int m = m0 + am;
    int b = m / 784, r = m % 784, t = r / 49, h = (r % 49) / 7, w = r % 7;
    aBase = (long)b * (512 * 1458) + t * 81 + h * 9 + w;
  }
  const float* __restrict__ Ap = Act + aBase;
  const int awb = am * 64, asw = (am & 7) << 3;   // swizzle in u16 units

  // staging ids: B (row bn, 16 k at bq*16; w1 row stride 13824 bf16 = 27648 B, 16B-aligned)
  const int bn = tid & 63, bq = tid >> 6;
  const u16* __restrict__ Bp = (const u16*)Wgt + (long)(n0 + bn) * 13824;
  const int bwb = bn * 64, bsw = (bn & 7) << 3;

  // compute ids
  const int lane = tid & 63, wv = tid >> 6;
  const int wm = (wv & 1) * 64, wn = (wv >> 1) * 32;
  const int lr = lane & 15, lq = lane >> 4;

  f32x4 acc[4][2];
#pragma unroll
  for (int i = 0; i < 4; ++i)
#pragma unroll
    for (int j = 0; j < 2; ++j) acc[i][j] = f32x4{0.f, 0.f, 0.f, 0.f};

  for (int k0 = 0; k0 < 13824; k0 += 64) {
    __syncthreads();
#pragma unroll
    for (int j = 0; j < 4; ++j) {
      const int o = k0 + khu * 32 + j * 8;
      const u16 e0 = b16u(Ap[koff[o + 0]]), e1 = b16u(Ap[koff[o + 1]]);
      const u16 e2 = b16u(Ap[koff[o + 2]]), e3 = b16u(Ap[koff[o + 3]]);
      const u16 e4 = b16u(Ap[koff[o + 4]]), e5 = b16u(Ap[koff[o + 5]]);
      const u16 e6 = b16u(Ap[koff[o + 6]]), e7 = b16u(Ap[koff[o + 7]]);
      u32x4 V = { (u32)e0 | ((u32)e1 << 16), (u32)e2 | ((u32)e3 << 16),
                  (u32)e4 | ((u32)e5 << 16), (u32)e6 | ((u32)e7 << 16) };
      *(u32x4*)&As[awb + ((khu * 32 + j * 8) ^ asw)] = V;
    }
    {
      const u32x4* wp = (const u32x4*)(Bp + k0 + bq * 16);
      *(u32x4*)&Bs[bwb + ((bq * 16) ^ bsw)] = wp[0];
      *(u32x4*)&Bs[bwb + ((bq * 16 + 8) ^ bsw)] = wp[1];
    }
    __syncthreads();
#pragma unroll
    for (int kk = 0; kk < 64; kk += 32) {
      const int kf = kk + lq * 8;
      s16x8 a[4], b[2];
#pragma unroll
      for (int fm = 0; fm < 4; ++fm) {
        const int row = wm + fm * 16 + lr;          // row&7 == lr&7
        a[fm] = *(const s16x8*)&As[row * 64 + (kf ^ ((lr & 7) << 3))];
      }
#pragma unroll
      for (int fn = 0; fn < 2; ++fn) {
        const int row = wn + fn * 16 + lr;
        b[fn] = *(const s16x8*)&Bs[row * 64 + (kf ^ ((lr & 7) << 3))];
      }
#pragma unroll
      for (int fm = 0; fm < 4; ++fm)
#pragma unroll
        for (int fn = 0; fn < 2; ++fn)
          acc[fm][fn] = __builtin_amdgcn_mfma_f32_16x16x32_bf16(a[fm], b[fn], acc[fm][fn], 0, 0, 0);
    }
  }

  // epilogue (C/D: col = lane&15 -> n, row = (lane>>4)*4 + reg -> m)  [m89-verified]
#pragma unroll
  for (int fn = 0; fn < 2; ++fn) {
    const int n = n0 + wn + fn * 16 + lr;
    const float bv = (float)(((const bf16_t*)bias)[n]);
#pragma unroll
    for (int fm = 0; fm < 4; ++fm)
#pragma unroll
      for (int r = 0; r < 4; ++r) {
        const int m = m0 + wm + fm * 16 + lq * 4 + r;
        int b = m / 784, rr = m % 784, t = rr / 49, hh = (rr % 49) / 7, ww = rr % 7;
        float v = fmaxf(acc[fm][fn][r] + bv, 0.f);
        Yt[(long)(b * 512 + n) * 1296 + t * 81 + (hh + 1) * 9 + (ww + 1)] = v;
      }
  }
}

// ---------- split-K reduce + bias + relu -> F global rows ----------
__global__ __launch_bounds__(256) void reduce2(const float* __restrict__ Part,
                                               const void* __restrict__ bias,
                                               float* __restrict__ F,
                                               const int* __restrict__ flagp, int chunk) {
  int f32m = *flagp;
  int idx = blockIdx.x * 256 + threadIdx.x;     // < 392*512
  if (idx >= 392 * 512) return;
  int m = idx >> 9, n = idx & 511;
  float v = 0.f;
  for (int s = 0; s < 4; s++) v += Part[((long)s * 392 + m) * 512 + n];
  v += ldf(bias, n, f32m);
  F[((long)chunk * 392 + m) * 512 + n] = fmaxf(v, 0.f);
}

// ---------- heads: 1x1 convs + pairwise softmax + bbox decode/clip (f32 OUTPUT) ----------
__global__ __launch_bounds__(256) void heads(
    const float* __restrict__ F, const void* __restrict__ cls_w, const void* __restrict__ cls_b,
    const void* __restrict__ bbox_w, const void* __restrict__ bbox_b,
    const void* __restrict__ im_info, float* __restrict__ out_cls, float* __restrict__ out_bbox,
    float* __restrict__ scores, float* __restrict__ boxes, const int* __restrict__ flagp) {
  int f32m = *flagp;
  int m = blockIdx.x;                       // 1568 = 32 img * 49
  int bg = m / 49, r2 = m % 49, h = r2 / 7, w = r2 % 7;
  __shared__ float Fr[512];
  __shared__ float partial[256];
  __shared__ float outv[54];
  int tid = threadIdx.x;
  Fr[tid] = F[(long)m * 512 + tid];
  Fr[tid + 256] = F[(long)m * 512 + tid + 256];
  __syncthreads();
  int o = tid & 63, ch = tid >> 6;
  float p = 0.f;
  if (o < 54) {
    const void* wp = (o < 18) ? cls_w : bbox_w;
    long wrow = (o < 18) ? (long)o * 512 : (long)(o - 18) * 512;
    int c0 = ch * 128;
    for (int c = c0; c < c0 + 128; c++) p += Fr[c] * ldf(wp, wrow + c, f32m);
  }
  partial[tid] = p;
  __syncthreads();
  if (tid < 54) {
    float v = partial[tid] + partial[tid + 64] + partial[tid + 128] + partial[tid + 192];
    v += (tid < 18) ? ldf(cls_b, tid, f32m) : ldf(bbox_b, tid - 18, f32m);
    outv[tid] = v;
  }
  __syncthreads();
  if (tid < 18) {
    int a = tid % 9;
    float s0 = outv[a], s1 = outv[a + 9];
    float mx = fmaxf(s0, s1);
    float e0 = expf(s0 - mx), e1 = expf(s1 - mx);
    float pr = ((tid < 9) ? e0 : e1) / (e0 + e1);
    if (!(pr == pr)) pr = 0.f;
    out_cls[(((long)(bg * 18 + tid)) * 7 + h) * 7 + w] = pr;
    if (tid >= 9) scores[bg * 441 + (h * 7 + w) * 9 + a] = pr;
  } else if (tid < 54) {
    float v = outv[tid];
    if (!(v == v)) v = 0.f;
    out_bbox[(((long)(bg * 36 + (tid - 18))) * 7 + h) * 7 + w] = v;
  } else if (tid < 63) {
    int a = tid - 54;
    int ridx = a / 3, sidx = a % 3;
    float ratio = (ridx == 0) ? 0.5f : ((ridx == 1) ? 1.f : 2.f);
    float scale = (sidx == 0) ? 4.f : ((sidx == 1) ? 8.f : 16.f);
    float ws0 = rintf(sqrtf(256.f / ratio));   // RNE == np.round
    float hs0 = rintf(ws0 * ratio);
    float x1 = 7.5f - 0.5f * (ws0 - 1.f), y1 = 7.5f - 0.5f * (hs0 - 1.f);
    float x2 = 7.5f + 0.5f * (ws0 - 1.f), y2 = 7.5f + 0.5f * (hs0 - 1.f);
    float w_ = x2 - x1 + 1.f, h_ = y2 - y1 + 1.f;
    float xc = x1 + 0.5f * (w_ - 1.f), yc = y1 + 0.5f * (h_ - 1.f);
    float ws2 = w_ * scale, hs2 = h_ * scale;
    float ax1 = xc - 0.5f * (ws2 - 1.f) + w * 16.f;
    float ay1 = yc - 0.5f * (hs2 - 1.f) + h * 16.f;
    float ax2 = xc + 0.5f * (ws2 - 1.f) + w * 16.f;
    float ay2 = yc + 0.5f * (hs2 - 1.f) + h * 16.f;
    float wA = ax2 - ax1 + 1.f, hA = ay2 - ay1 + 1.f;
    float cxA = ax1 + 0.5f * wA, cyA = ay1 + 0.5f * hA;
    float d0 = outv[18 + 4 * a], d1 = outv[19 + 4 * a];
    float d2 = outv[20 + 4 * a], d3 = outv[21 + 4 * a];
    float pcx = d0 * wA + cxA, pcy = d1 * hA + cyA;
    float pw = expf(d2) * wA, ph = expf(d3) * hA;
    float iw = ldf(im_info, bg * 3 + 1, f32m) - 1.f;
    float ih = ldf(im_info, bg * 3 + 0, f32m) - 1.f;
    float bx1 = clampf(pcx - 0.5f * pw, 0.f, iw);
    float by1 = clampf(pcy - 0.5f * ph, 0.f, ih);
    float bx2 = clampf(pcx + 0.5f * pw, 0.f, iw);
    float by2 = clampf(pcy + 0.5f * ph, 0.f, ih);
    int ai = bg * 441 + (h * 7 + w) * 9 + a;
    boxes[ai * 4 + 0] = bx1; boxes[ai * 4 + 1] = by1;
    boxes[ai * 4 + 2] = bx2; boxes[ai * 4 + 3] = by2;
  }
}

// ---------- per-image greedy NMS (stable rank, bitmask suppression; f32 OUTPUT) ----------
__global__ __launch_bounds__(256) void nms_kernel(const float* __restrict__ scores,
                                                  const float* __restrict__ boxes,
                                                  float* __restrict__ rois) {
  int bg = blockIdx.x;
  int tid = threadIdx.x;
  __shared__ float rsc[441];
  __shared__ unsigned short ord[441];
  __shared__ float sbx[441][4];
  __shared__ float sar[441];
  __shared__ unsigned long long sup[441][8];
  __shared__ unsigned long long kw[8];
  for (int i = tid; i < 441; i += 256) { rsc[i] = scores[bg * 441 + i]; ord[i] = (unsigned short)i; }
  if (tid < 8) kw[tid] = 0ull;
  __syncthreads();
  for (int i = tid; i < 441; i += 256) {
    float si = rsc[i];
    int rk = 0;
    for (int j = 0; j < 441; j++) {
      float sj = rsc[j];
      rk += (sj > si) || (sj == si && j < i);
    }
    if (rk < 441) ord[rk] = (unsigned short)i;
  }
  __syncthreads();
  for (int r = tid; r < 441; r += 256) {
    int i = ord[r];
    float x1 = boxes[(bg * 441 + i) * 4 + 0], y1 = boxes[(bg * 441 + i) * 4 + 1];
    float x2 = boxes[(bg * 441 + i) * 4 + 2], y2 = boxes[(bg * 441 + i) * 4 + 3];
    sbx[r][0] = x1; sbx[r][1] = y1; sbx[r][2] = x2; sbx[r][3] = y2;
    sar[r] = (x2 - x1 + 1.f) * (y2 - y1 + 1.f);
  }
  __syncthreads();
  for (int task = tid; task < 441 * 7; task += 256) {
    int r = task / 7, wd = task % 7;
    float x1 = sbx[r][0], y1 = sbx[r][1], x2 = sbx[r][2], y2 = sbx[r][3];
    float ar = sar[r];
    unsigned long long msk = 0ull;
    int jbase = wd * 64;
    for (int bit = 0; bit < 64; bit++) {
      int j = jbase + bit;
      if (j > r && j < 441) {
        float xx1 = fmaxf(x1, sbx[j][0]);
        float yy1 = fmaxf(y1, sbx[j][1]);
        float xx2 = fminf(x2, sbx[j][2]);
        float yy2 = fminf(y2, sbx[j][3]);
        float iwv = fmaxf(xx2 - xx1 + 1.f, 0.f);
        float ihv = fmaxf(yy2 - yy1 + 1.f, 0.f);
        float inter = iwv * ihv;
        float iou = inter / (ar + sar[j] - inter);
        if (iou > 0.7f) msk |= (1ull << bit);
      }
    }
    sup[r][wd] = msk;
  }
  __syncthreads();
  if (tid < 64) {
    int wd = (tid < 7) ? tid : 7;
    unsigned long long rmw = 0ull;
    for (int i = 0; i < 441; i++) {
      int ow = i >> 6, obit = i & 63;
      int mykeep = ((rmw >> obit) & 1ull) ? 0 : 1;
      int kept = __shfl(mykeep, ow, 64);
      if (kept && wd < 7) rmw |= sup[i][wd];
    }
    if (wd < 7) {
      unsigned long long k = ~rmw;
      if (wd == 6) k &= (1ull << 57) - 1;   // 441 bits total
      kw[wd] = k;
    }
  }
  __syncthreads();
  for (int r = tid; r < POSTN; r += 256) {
    long oo = ((long)bg * POSTN + r) * 5;
    rois[oo] = (float)bg;
    rois[oo + 1] = 0.f; rois[oo + 2] = 0.f;
    rois[oo + 3] = 0.f; rois[oo + 4] = 0.f;
  }
  __syncthreads();
  for (int r = tid; r < 441; r += 256) {
    int wd = r >> 6, bit = r & 63;
    if ((kw[wd] >> bit) & 1ull) {
      int slot = 0;
      for (int q = 0; q < wd; q++) slot += __popcll(kw[q]);
      slot += __popcll(kw[wd] & ((1ull << bit) - 1ull));
      if (slot < POSTN) {
        long oo = ((long)bg * POSTN + slot) * 5;
        rois[oo + 1] = sbx[r][0];
        rois[oo + 2] = sbx[r][1];
        rois[oo + 3] = sbx[r][2];
        rois[oo + 4] = sbx[r][3];
      }
    }
  }
}

// ---------- final scrub: non-finite f32 -> 0 (safety net) ----------
__global__ __launch_bounds__(256) void scrub_f32(float* __restrict__ o, int n) {
  int i = blockIdx.x * 256 + threadIdx.x;
  if (i >= n) return;
  float v = o[i];
  if (!(v == v) || fabsf(v) > 1e30f) o[i] = 0.f;
}

__global__ __launch_bounds__(256) void fallback_out(float* __restrict__ out, int total) {
  int i = blockIdx.x * 256 + threadIdx.x;
  if (i >= total) return;
  out[i] = 0.f;
}

extern "C" void kernel_launch(void* const* d_in, const int* in_sizes, int n_in,
                              void* d_out, int out_size, void* d_ws, size_t ws_size,
                              hipStream_t stream) {
  const void* base_feat = d_in[0];
  const void* im_info   = d_in[1];
  const void* w1 = d_in[4];
  const void* b1 = d_in[5];
  const void* w2 = d_in[6];
  const void* b2 = d_in[7];
  const void* cw = d_in[8];
  const void* cb = d_in[9];
  const void* bw = d_in[10];
  const void* bb = d_in[11];
  float* out = (float*)d_out;   // reference output dtype = float32

  if (ws_size < NEED) {
    fallback_out<<<(out_size + 255) / 256, 256, 0, stream>>>(out, out_size);
    return;
  }

  char* ws = (char*)d_ws;
  float* XpT  = (float*)(ws + XPT_OFF);
  float* Yt   = (float*)(ws + YT_OFF);
  float* F    = (float*)(ws + F_OFF);
  float* Part = (float*)(ws + PART_OFF);
  float* Sc   = (float*)(ws + SC_OFF);
  float* Bx   = (float*)(ws + BX_OFF);
  int*   K1   = (int*)(ws + K1_OFF);
  int*   K2   = (int*)(ws + K2_OFF);
  int*   Flag = (int*)(ws + FLAG_OFF);

  detect_dtype<<<1, 256, 0, stream>>>(base_feat, w1, Flag);
  build_koff<<<288, 256, 0, stream>>>(K1, K2);

  for (int c = 0; c < 4; c++) {
    hipMemsetAsync(XpT, 0, 23887872ull, stream);   // halos
    hipMemsetAsync(Yt, 0, 21233664ull, stream);    // spatial borders
    pad_x<<<12544, 256, 0, stream>>>(base_feat, XpT, Flag, c * 8);
    gemm_f32<1><<<784, 256, 0, stream>>>(XpT, w1, b1, Yt, nullptr, K1, Flag);   // f32 mode
    gemm_mf1<<<392, 256, 0, stream>>>(XpT, w1, b1, Yt, K1, Flag);               // bf16 mode (MFMA)
    gemm_f32<2><<<224, 256, 0, stream>>>(Yt, w2, nullptr, nullptr, Part, K2, Flag);
    reduce2<<<784, 256, 0, stream>>>(Part, b2, F, Flag, c);
  }

  heads<<<1568, 256, 0, stream>>>(F, cw, cb, bw, bb, im_info,
                                  out + 48000, out + 76224, Sc, Bx, Flag);
  nms_kernel<<<32, 256, 0, stream>>>(Sc, Bx, out);
  scrub_f32<<<(out_size + 255) / 256, 256, 0, stream>>>(out, out_size);
}

// Round 5
// 10348.226 us; speedup vs baseline: 1.5055x; 1.2220x over previous
//
#include <hip/hip_runtime.h>
#include <hip/hip_bf16.h>
#include <cmath>

typedef __bf16 bf16_t;
typedef unsigned short u16;
typedef unsigned int u32;
typedef float f32x4 __attribute__((ext_vector_type(4)));
typedef short s16x8 __attribute__((ext_vector_type(8)));
typedef u32   u32x4 __attribute__((ext_vector_type(4)));
#define DEVINL __device__ __forceinline__
#define POSTN 300

// ---- workspace layout (bytes). NEED = 52,176,516 ---- (round-0 layout, verified)
// f32-input mode: XpT f32 [0..23.9M), Yt f32 [23.9M..45.1M)  (round-0, unchanged)
// bf16-input mode: Xp16 u16 [0..11.94M), YtL u16 [11.94M..22.56M),
//                  YtHM u32 [23.9M..45.1M)   (modes never mix; flag-branched)
#define XPT_OFF  0ull           // 23,887,872
#define YTL_OFF  11943936ull    // 10,616,832 u16 (bf16 mode only; inside old XpT region)
#define YT_OFF   23887872ull    // 21,233,664
#define F_OFF    45121536ull    // [1568][512] f32 = 3,211,264
#define PART_OFF 48332800ull    // [4][392][512] f32 = 3,211,264
#define SC_OFF   51544064ull    // [32*441] f32
#define BX_OFF   51600512ull    // [32*441*4] f32
#define K1_OFF   51826304ull    // [13824] int
#define K2_OFF   51881600ull    // [73728] int
#define FLAG_OFF 52176512ull
#define NEED     52176516ull

// dtype-branched float load (flag: 1 = inputs are f32, 0 = bf16)
DEVINL float ldf(const void* p, long i, int f32m) {
  return f32m ? ((const float*)p)[i] : (float)(((const bf16_t*)p)[i]);
}

// NaN-safe clamp (NaN -> lo), not foldable to bare v_med3
DEVINL float clampf(float v, float lo, float hi) {
  if (!(v == v)) return lo;
  if (v < lo) return lo;
  if (v > hi) return hi;
  return v;
}

// exact 3-word bf16 split: v == h + m + l (error-free transform of f32)
DEVINL void split3(float v, u16& hb, u16& mb, u16& lb) {
  bf16_t h = (bf16_t)v; float fh = (float)h;
  float r1 = v - fh;                        // exact
  bf16_t m = (bf16_t)r1; float fm_ = (float)m;
  float r2 = r1 - fm_;                      // exact; <=8 significant bits left
  bf16_t l = (bf16_t)r2;                    // exact
  __builtin_memcpy(&hb, &h, 2);
  __builtin_memcpy(&mb, &m, 2);
  __builtin_memcpy(&lb, &l, 2);
}

// ---------- input dtype detector ----------
__global__ __launch_bounds__(256) void detect_dtype(const void* bf, const void* w1, int* flag) {
  __shared__ int cnt;
  int tid = threadIdx.x;
  if (tid == 0) cnt = 0;
  __syncthreads();
  // even-indexed bf16 decodes are garbage iff underlying data is f32 (low mantissa bits)
  float a = (float)(((const bf16_t*)bf)[2 * tid]);
  float b = (float)(((const bf16_t*)w1)[2 * tid]);
  int wc = 0;
  if (!(a == a) || fabsf(a) > 1e20f || (a != 0.f && fabsf(a) < 1e-20f)) wc++;
  if (!(b == b) || fabsf(b) > 1e20f || (b != 0.f && fabsf(b) < 1e-20f)) wc++;
  atomicAdd(&cnt, wc);
  __syncthreads();
  if (tid == 0) *flag = (cnt >= 16) ? 1 : 0;
}

// ---------- k -> activation-offset tables ----------
__global__ __launch_bounds__(256) void build_koff(int* k1, int* k2) {
  int i = blockIdx.x * 256 + threadIdx.x;
  if (i < 13824) {               // k = ci*27 + tap ; Xp ci-stride 1458
    int ci = i / 27, tap = i % 27;
    k1[i] = ci * 1458 + (tap / 9) * 81 + ((tap % 9) / 3) * 9 + (tap % 3);
  }
  if (i < 73728) {               // k = ci*144 + tap ; Yt ci-stride 1296
    int ci = i / 144, tap = i % 144;
    k2[i] = ci * 1296 + (tap / 9) * 81 + ((tap % 9) / 3) * 9 + (tap % 3);
  }
}

// ---------- pad copy: X[b][ci][t][h][w] -> Xp[b][ci][t+1][h+1][w+1] (mode-branched) ----------
__global__ __launch_bounds__(256) void pad_x(const void* __restrict__ X,
                                             float* __restrict__ XpT, u16* __restrict__ Xp16,
                                             const int* __restrict__ flagp, int cb) {
  int f32m = *flagp;
  long e = (long)blockIdx.x * 256 + threadIdx.x;      // < 8*512*784
  if (e >= 8L * 512 * 784) return;
  int f = (int)(e % 784);
  long bc = e / 784;                                   // local_b*512 + ci
  int t = f / 49, h = (f % 49) / 7, w = f % 7;
  long src = (long)cb * 512 * 784 + bc * 784 + f;
  long idx = bc * 1458 + (t + 1) * 81 + (h + 1) * 9 + (w + 1);
  if (f32m) XpT[idx] = ((const float*)X)[src];
  else      Xp16[idx] = ((const u16*)X)[src];          // input IS bf16: raw copy
}

// ---------- f32 tiled GEMM (VALU; f32-input mode ONLY — round-0 verified) ----------
template <int MODE>
__global__ __launch_bounds__(256) void gemm_f32(
    const float* __restrict__ Act, const void* __restrict__ Wgt, const void* __restrict__ bias,
    float* __restrict__ Yt, float* __restrict__ Part,
    const int* __restrict__ koff, const int* __restrict__ flagp) {
  const int f32m = *flagp;
  if (f32m == 0) return;                  // bf16 mode: MFMA kernels own both convs
  const int tid = threadIdx.x;
  int mt, nt, s = 0;
  if (MODE == 1) { mt = blockIdx.x % 98; nt = blockIdx.x / 98; }
  else           { mt = blockIdx.x % 7;  nt = (blockIdx.x / 7) % 8; s = blockIdx.x / 56; }
  const int m0 = mt * 64, n0 = nt * 64;
  const int K     = (MODE == 1) ? 13824 : 18432;     // k-extent (per split for MODE 2)
  const int kBase = (MODE == 1) ? 0     : s * 18432;
  const int WROW  = (MODE == 1) ? 13824 : 73728;

  __shared__ __align__(16) float As[64][68];   // [k][m], +4 pad
  __shared__ __align__(16) float Bs[64][68];   // [k][n]

  const int am = tid & 63, akq = tid >> 6;
  long aBase;
  {
    int m = m0 + am;
    if (MODE == 1) {
      int b = m / 784, r = m % 784, t = r / 49, h = (r % 49) / 7, w = r % 7;
      aBase = (long)b * (512 * 1458) + t * 81 + h * 9 + w;
    } else {
      if (m > 391) m = 391;
      int b = m / 49, r = m % 49, h = r / 7, w = r % 7;
      aBase = (long)b * (512 * 1296) + h * 9 + w;
    }
  }
  const int bn = tid >> 2, bks = (tid & 3) * 16;
  const long bBase = (long)(n0 + bn) * WROW + kBase;

  float acc[4][4] = {{0.f}};
  const int tx = tid & 15, ty = tid >> 4;

  for (int k0 = 0; k0 < K; k0 += 64) {
    __syncthreads();
#pragma unroll
    for (int j = 0; j < 16; j++) {
      int kk = akq * 16 + j;
      As[kk][am] = Act[aBase + koff[kBase + k0 + kk]];
    }
#pragma unroll
    for (int j = 0; j < 16; j++) {
      int kk = bks + j;
      Bs[kk][bn] = ldf(Wgt, bBase + k0 + kk, f32m);
    }
    __syncthreads();
#pragma unroll 8
    for (int k = 0; k < 64; k++) {
      f32x4 a = *(const f32x4*)&As[k][tx * 4];
      f32x4 b = *(const f32x4*)&Bs[k][ty * 4];
#pragma unroll
      for (int i = 0; i < 4; i++)
#pragma unroll
        for (int j = 0; j < 4; j++) acc[i][j] += a[i] * b[j];
    }
  }

#pragma unroll
  for (int i = 0; i < 4; i++) {
    int m = m0 + tx * 4 + i;
#pragma unroll
    for (int j = 0; j < 4; j++) {
      int n = n0 + ty * 4 + j;
      if (MODE == 1) {
        int b = m / 784, r = m % 784, t = r / 49, h = (r % 49) / 7, w = r % 7;
        float v = acc[i][j] + ldf(bias, n, f32m);
        v = fmaxf(v, 0.f);
        Yt[(long)(b * 512 + n) * 1296 + t * 81 + (h + 1) * 9 + (w + 1)] = v;
      } else {
        if (m < 392) Part[((long)s * 392 + m) * 512 + n] = acc[i][j];
      }
    }
  }
}

// ---------- MFMA conv1 (bf16 mode; exact products, f32 accumulation) ----------
// A[m=(b,t,h,w)][k] gathered from u16 Xp16; B = w1 rows (native bf16).
// Block tile 128x64, BK=64, 4 waves, wave 64x32 = 4x2 frags of mfma 16x16x32.
// Epilogue: bias+relu then exact 3-word split -> YtHM (h<<16|m) + YtL planes.
__global__ __launch_bounds__(256) void gemm_mf1(
    const u16* __restrict__ Act16, const void* __restrict__ Wgt, const void* __restrict__ bias,
    u32* __restrict__ YtHM, u16* __restrict__ YtL,
    const int* __restrict__ koff, const int* __restrict__ flagp) {
  if (*flagp != 0) return;            // f32-input mode handled by gemm_f32<1>
  const int tid = threadIdx.x;
  const int mt = blockIdx.x % 49, nt = blockIdx.x / 49;   // 392 blocks, M=6272 exact
  const int m0 = mt * 128, n0 = nt * 64;

  __shared__ u16 As[128 * 64];
  __shared__ u16 Bs[64 * 64];

  // staging ids: A (each of 256 threads stages one row-half: 32 k gathers)
  const int am = tid & 127, khu = tid >> 7;
  long aBase;
  {
    int m = m0 + am;
    int b = m / 784, r = m % 784, t = r / 49, h = (r % 49) / 7, w = r % 7;
    aBase = (long)b * (512 * 1458) + t * 81 + h * 9 + w;
  }
  const u16* __restrict__ Ap = Act16 + aBase;
  const int awb = am * 64, asw = (am & 7) << 3;   // swizzle in u16 units

  // staging ids: B (row bn, 16 k at bq*16)
  const int bn = tid & 63, bq = tid >> 6;
  const u16* __restrict__ Bp = (const u16*)Wgt + (long)(n0 + bn) * 13824;
  const int bwb = bn * 64, bsw = (bn & 7) << 3;

  // compute ids
  const int lane = tid & 63, wv = tid >> 6;
  const int wm = (wv & 1) * 64, wn = (wv >> 1) * 32;
  const int lr = lane & 15, lq = lane >> 4;

  f32x4 acc[4][2];
#pragma unroll
  for (int i = 0; i < 4; ++i)
#pragma unroll
    for (int j = 0; j < 2; ++j) acc[i][j] = f32x4{0.f, 0.f, 0.f, 0.f};

  for (int k0 = 0; k0 < 13824; k0 += 64) {
    __syncthreads();
#pragma unroll
    for (int j = 0; j < 4; ++j) {
      const int o = k0 + khu * 32 + j * 8;
      const u16 e0 = Ap[koff[o + 0]], e1 = Ap[koff[o + 1]];
      const u16 e2 = Ap[koff[o + 2]], e3 = Ap[koff[o + 3]];
      const u16 e4 = Ap[koff[o + 4]], e5 = Ap[koff[o + 5]];
      const u16 e6 = Ap[koff[o + 6]], e7 = Ap[koff[o + 7]];
      u32x4 V = { (u32)e0 | ((u32)e1 << 16), (u32)e2 | ((u32)e3 << 16),
                  (u32)e4 | ((u32)e5 << 16), (u32)e6 | ((u32)e7 << 16) };
      *(u32x4*)&As[awb + ((khu * 32 + j * 8) ^ asw)] = V;
    }
    {
      const u32x4* wp = (const u32x4*)(Bp + k0 + bq * 16);
      *(u32x4*)&Bs[bwb + ((bq * 16) ^ bsw)] = wp[0];
      *(u32x4*)&Bs[bwb + ((bq * 16 + 8) ^ bsw)] = wp[1];
    }
    __syncthreads();
#pragma unroll
    for (int kk = 0; kk < 64; kk += 32) {
      const int kf = kk + lq * 8;
      s16x8 a[4], b[2];
#pragma unroll
      for (int fm = 0; fm < 4; ++fm) {
        const int row = wm + fm * 16 + lr;          // row&7 == lr&7
        a[fm] = *(const s16x8*)&As[row * 64 + (kf ^ ((lr & 7) << 3))];
      }
#pragma unroll
      for (int fn = 0; fn < 2; ++fn) {
        const int row = wn + fn * 16 + lr;
        b[fn] = *(const s16x8*)&Bs[row * 64 + (kf ^ ((lr & 7) << 3))];
      }
#pragma unroll
      for (int fm = 0; fm < 4; ++fm)
#pragma unroll
        for (int fn = 0; fn < 2; ++fn)
          acc[fm][fn] = __builtin_amdgcn_mfma_f32_16x16x32_bf16(a[fm], b[fn], acc[fm][fn], 0, 0, 0);
    }
  }

  // epilogue (C/D: col = lane&15 -> n, row = (lane>>4)*4 + reg -> m)
#pragma unroll
  for (int fn = 0; fn < 2; ++fn) {
    const int n = n0 + wn + fn * 16 + lr;
    const float bv = (float)(((const bf16_t*)bias)[n]);
#pragma unroll
    for (int fm = 0; fm < 4; ++fm)
#pragma unroll
      for (int r = 0; r < 4; ++r) {
        const int m = m0 + wm + fm * 16 + lq * 4 + r;
        int b = m / 784, rr = m % 784, t = rr / 49, hh = (rr % 49) / 7, ww = rr % 7;
        float v = fmaxf(acc[fm][fn][r] + bv, 0.f);
        u16 hb, mb, lb; split3(v, hb, mb, lb);
        long idx = (long)(b * 512 + n) * 1296 + t * 81 + (hh + 1) * 9 + (ww + 1);
        YtHM[idx] = ((u32)hb << 16) | mb;
        YtL[idx] = lb;
      }
  }
}

// ---------- MFMA conv2 (bf16 mode; A = exact h+m+l planes, B exact bf16) ----------
// Block tile 64x64, BK=64, 4 waves, wave 32x32 = 2x2 frags. 3 MFMA passes (h,m,l).
// Grid 224: mt(7) x nt(8) x splitK s(4, 18432 each). Epilogue -> Part (round-0 layout).
__global__ __launch_bounds__(256) void gemm_mf2(
    const u32* __restrict__ AHM, const u16* __restrict__ AL, const void* __restrict__ Wgt,
    float* __restrict__ Part, const int* __restrict__ koff, const int* __restrict__ flagp) {
  if (*flagp != 0) return;            // f32-input mode handled by gemm_f32<2>
  const int tid = threadIdx.x;
  const int mt = blockIdx.x % 7, nt = (blockIdx.x / 7) % 8, s = blockIdx.x / 56;
  const int m0 = mt * 64, n0 = nt * 64;
  const int kBase = s * 18432;

  __shared__ u16 AsH[64 * 64], AsM[64 * 64], AsL[64 * 64];
  __shared__ u16 Bs[64 * 64];

  // staging ids: A (row am, quarter kq: 16 k gathers as 2 groups of 8)
  const int am = tid & 63, kq = tid >> 6;
  long aBase;
  {
    int m = m0 + am; if (m > 391) m = 391;
    int b = m / 49, r = m % 49, h = r / 7, w = r % 7;
    aBase = (long)b * (512 * 1296) + h * 9 + w;
  }
  const u32* __restrict__ ApHM = AHM + aBase;
  const u16* __restrict__ ApL  = AL + aBase;
  const int awb = am * 64, asw = (am & 7) << 3;

  // staging ids: B (w2 bf16 rows, stride 73728)
  const int bn = tid & 63, bq = tid >> 6;
  const u16* __restrict__ Bp = (const u16*)Wgt + (long)(n0 + bn) * 73728 + kBase;
  const int bwb = bn * 64, bsw = (bn & 7) << 3;

  // compute ids
  const int lane = tid & 63, wv = tid >> 6;
  const int wm = (wv & 1) * 32, wn = (wv >> 1) * 32;
  const int lr = lane & 15, lq = lane >> 4;

  f32x4 acc[2][2];
#pragma unroll
  for (int i = 0; i < 2; ++i)
#pragma unroll
    for (int j = 0; j < 2; ++j) acc[i][j] = f32x4{0.f, 0.f, 0.f, 0.f};

  for (int k0 = 0; k0 < 18432; k0 += 64) {
    __syncthreads();
#pragma unroll
    for (int g = 0; g < 2; ++g) {
      const int o = kBase + k0 + kq * 16 + g * 8;
      const int i0 = koff[o + 0], i1 = koff[o + 1], i2 = koff[o + 2], i3 = koff[o + 3],
                i4 = koff[o + 4], i5 = koff[o + 5], i6 = koff[o + 6], i7 = koff[o + 7];
      const u32 q0 = ApHM[i0], q1 = ApHM[i1], q2 = ApHM[i2], q3 = ApHM[i3],
                q4 = ApHM[i4], q5 = ApHM[i5], q6 = ApHM[i6], q7 = ApHM[i7];
      const int wi = awb + ((kq * 16 + g * 8) ^ asw);
      u32x4 H = { (q0 >> 16) | (q1 & 0xffff0000u), (q2 >> 16) | (q3 & 0xffff0000u),
                  (q4 >> 16) | (q5 & 0xffff0000u), (q6 >> 16) | (q7 & 0xffff0000u) };
      *(u32x4*)&AsH[wi] = H;
      u32x4 M = { (q0 & 0xffffu) | (q1 << 16), (q2 & 0xffffu) | (q3 << 16),
                  (q4 & 0xffffu) | (q5 << 16), (q6 & 0xffffu) | (q7 << 16) };
      *(u32x4*)&AsM[wi] = M;
      u32x4 L = { (u32)ApL[i0] | ((u32)ApL[i1] << 16), (u32)ApL[i2] | ((u32)ApL[i3] << 16),
                  (u32)ApL[i4] | ((u32)ApL[i5] << 16), (u32)ApL[i6] | ((u32)ApL[i7] << 16) };
      *(u32x4*)&AsL[wi] = L;
    }
    {
      const u32x4* wp = (const u32x4*)(Bp + k0 + bq * 16);
      *(u32x4*)&Bs[bwb + ((bq * 16) ^ bsw)] = wp[0];
      *(u32x4*)&Bs[bwb + ((bq * 16 + 8) ^ bsw)] = wp[1];
    }
    __syncthreads();
#pragma unroll
    for (int kk = 0; kk < 64; kk += 32) {
      const int kf = kk + lq * 8;
      s16x8 ah[2], am_[2], al[2], b[2];
#pragma unroll
      for (int fm = 0; fm < 2; ++fm) {
        const int off = (wm + fm * 16 + lr) * 64 + (kf ^ ((lr & 7) << 3));
        ah[fm] = *(const s16x8*)&AsH[off];
        am_[fm] = *(const s16x8*)&AsM[off];
        al[fm] = *(const s16x8*)&AsL[off];
      }
#pragma unroll
      for (int fn = 0; fn < 2; ++fn) {
        const int off = (wn + fn * 16 + lr) * 64 + (kf ^ ((lr & 7) << 3));
        b[fn] = *(const s16x8*)&Bs[off];
      }
#pragma unroll
      for (int fm = 0; fm < 2; ++fm)
#pragma unroll
        for (int fn = 0; fn < 2; ++fn) {
          acc[fm][fn] = __builtin_amdgcn_mfma_f32_16x16x32_bf16(ah[fm], b[fn], acc[fm][fn], 0, 0, 0);
          acc[fm][fn] = __builtin_amdgcn_mfma_f32_16x16x32_bf16(am_[fm], b[fn], acc[fm][fn], 0, 0, 0);
          acc[fm][fn] = __builtin_amdgcn_mfma_f32_16x16x32_bf16(al[fm], b[fn], acc[fm][fn], 0, 0, 0);
        }
    }
  }

  // epilogue -> Part (split-K partials; round-0 layout, reduce2 unchanged)
#pragma unroll
  for (int fn = 0; fn < 2; ++fn) {
    const int n = n0 + wn + fn * 16 + lr;
#pragma unroll
    for (int fm = 0; fm < 2; ++fm)
#pragma unroll
      for (int r = 0; r < 4; ++r) {
        const int m = m0 + wm + fm * 16 + lq * 4 + r;
        if (m < 392) Part[((long)s * 392 + m) * 512 + n] = acc[fm][fn][r];
      }
  }
}

// ---------- split-K reduce + bias + relu -> F global rows ----------
__global__ __launch_bounds__(256) void reduce2(const float* __restrict__ Part,
                                               const void* __restrict__ bias,
                                               float* __restrict__ F,
                                               const int* __restrict__ flagp, int chunk) {
  int f32m = *flagp;
  int idx = blockIdx.x * 256 + threadIdx.x;     // < 392*512
  if (idx >= 392 * 512) return;
  int m = idx >> 9, n = idx & 511;
  float v = 0.f;
  for (int s = 0; s < 4; s++) v += Part[((long)s * 392 + m) * 512 + n];
  v += ldf(bias, n, f32m);
  F[((long)chunk * 392 + m) * 512 + n] = fmaxf(v, 0.f);
}

// ---------- heads: 1x1 convs + pairwise softmax + bbox decode/clip (f32 OUTPUT) ----------
__global__ __launch_bounds__(256) void heads(
    const float* __restrict__ F, const void* __restrict__ cls_w, const void* __restrict__ cls_b,
    const void* __restrict__ bbox_w, const void* __restrict__ bbox_b,
    const void* __restrict__ im_info, float* __restrict__ out_cls, float* __restrict__ out_bbox,
    float* __restrict__ scores, float* __restrict__ boxes, const int* __restrict__ flagp) {
  int f32m = *flagp;
  int m = blockIdx.x;                       // 1568 = 32 img * 49
  int bg = m / 49, r2 = m % 49, h = r2 / 7, w = r2 % 7;
  __shared__ float Fr[512];
  __shared__ float partial[256];
  __shared__ float outv[54];
  int tid = threadIdx.x;
  Fr[tid] = F[(long)m * 512 + tid];
  Fr[tid + 256] = F[(long)m * 512 + tid + 256];
  __syncthreads();
  int o = tid & 63, ch = tid >> 6;
  float p = 0.f;
  if (o < 54) {
    const void* wp = (o < 18) ? cls_w : bbox_w;
    long wrow = (o < 18) ? (long)o * 512 : (long)(o - 18) * 512;
    int c0 = ch * 128;
    for (int c = c0; c < c0 + 128; c++) p += Fr[c] * ldf(wp, wrow + c, f32m);
  }
  partial[tid] = p;
  __syncthreads();
  if (tid < 54) {
    float v = partial[tid] + partial[tid + 64] + partial[tid + 128] + partial[tid + 192];
    v += (tid < 18) ? ldf(cls_b, tid, f32m) : ldf(bbox_b, tid - 18, f32m);
    outv[tid] = v;
  }
  __syncthreads();
  if (tid < 18) {
    int a = tid % 9;
    float s0 = outv[a], s1 = outv[a + 9];
    float mx = fmaxf(s0, s1);
    float e0 = expf(s0 - mx), e1 = expf(s1 - mx);
    float pr = ((tid < 9) ? e0 : e1) / (e0 + e1);
    if (!(pr == pr)) pr = 0.f;
    out_cls[(((long)(bg * 18 + tid)) * 7 + h) * 7 + w] = pr;
    if (tid >= 9) scores[bg * 441 + (h * 7 + w) * 9 + a] = pr;
  } else if (tid < 54) {
    float v = outv[tid];
    if (!(v == v)) v = 0.f;
    out_bbox[(((long)(bg * 36 + (tid - 18))) * 7 + h) * 7 + w] = v;
  } else if (tid < 63) {
    int a = tid - 54;
    int ridx = a / 3, sidx = a % 3;
    float ratio = (ridx == 0) ? 0.5f : ((ridx == 1) ? 1.f : 2.f);
    float scale = (sidx == 0) ? 4.f : ((sidx == 1) ? 8.f : 16.f);
    float ws0 = rintf(sqrtf(256.f / ratio));   // RNE == np.round
    float hs0 = rintf(ws0 * ratio);
    float x1 = 7.5f - 0.5f * (ws0 - 1.f), y1 = 7.5f - 0.5f * (hs0 - 1.f);
    float x2 = 7.5f + 0.5f * (ws0 - 1.f), y2 = 7.5f + 0.5f * (hs0 - 1.f);
    float w_ = x2 - x1 + 1.f, h_ = y2 - y1 + 1.f;
    float xc = x1 + 0.5f * (w_ - 1.f), yc = y1 + 0.5f * (h_ - 1.f);
    float ws2 = w_ * scale, hs2 = h_ * scale;
    float ax1 = xc - 0.5f * (ws2 - 1.f) + w * 16.f;
    float ay1 = yc - 0.5f * (hs2 - 1.f) + h * 16.f;
    float ax2 = xc + 0.5f * (ws2 - 1.f) + w * 16.f;
    float ay2 = yc + 0.5f * (hs2 - 1.f) + h * 16.f;
    float wA = ax2 - ax1 + 1.f, hA = ay2 - ay1 + 1.f;
    float cxA = ax1 + 0.5f * wA, cyA = ay1 + 0.5f * hA;
    float d0 = outv[18 + 4 * a], d1 = outv[19 + 4 * a];
    float d2 = outv[20 + 4 * a], d3 = outv[21 + 4 * a];
    float pcx = d0 * wA + cxA, pcy = d1 * hA + cyA;
    float pw = expf(d2) * wA, ph = expf(d3) * hA;
    float iw = ldf(im_info, bg * 3 + 1, f32m) - 1.f;
    float ih = ldf(im_info, bg * 3 + 0, f32m) - 1.f;
    float bx1 = clampf(pcx - 0.5f * pw, 0.f, iw);
    float by1 = clampf(pcy - 0.5f * ph, 0.f, ih);
    float bx2 = clampf(pcx + 0.5f * pw, 0.f, iw);
    float by2 = clampf(pcy + 0.5f * ph, 0.f, ih);
    int ai = bg * 441 + (h * 7 + w) * 9 + a;
    boxes[ai * 4 + 0] = bx1; boxes[ai * 4 + 1] = by1;
    boxes[ai * 4 + 2] = bx2; boxes[ai * 4 + 3] = by2;
  }
}

// ---------- per-image greedy NMS (stable rank, bitmask suppression; f32 OUTPUT) ----------
__global__ __launch_bounds__(256) void nms_kernel(const float* __restrict__ scores,
                                                  const float* __restrict__ boxes,
                                                  float* __restrict__ rois) {
  int bg = blockIdx.x;
  int tid = threadIdx.x;
  __shared__ float rsc[441];
  __shared__ unsigned short ord[441];
  __shared__ float sbx[441][4];
  __shared__ float sar[441];
  __shared__ unsigned long long sup[441][8];
  __shared__ unsigned long long kw[8];
  for (int i = tid; i < 441; i += 256) { rsc[i] = scores[bg * 441 + i]; ord[i] = (unsigned short)i; }
  if (tid < 8) kw[tid] = 0ull;
  __syncthreads();
  for (int i = tid; i < 441; i += 256) {
    float si = rsc[i];
    int rk = 0;
    for (int j = 0; j < 441; j++) {
      float sj = rsc[j];
      rk += (sj > si) || (sj == si && j < i);
    }
    if (rk < 441) ord[rk] = (unsigned short)i;
  }
  __syncthreads();
  for (int r = tid; r < 441; r += 256) {
    int i = ord[r];
    float x1 = boxes[(bg * 441 + i) * 4 + 0], y1 = boxes[(bg * 441 + i) * 4 + 1];
    float x2 = boxes[(bg * 441 + i) * 4 + 2], y2 = boxes[(bg * 441 + i) * 4 + 3];
    sbx[r][0] = x1; sbx[r][1] = y1; sbx[r][2] = x2; sbx[r][3] = y2;
    sar[r] = (x2 - x1 + 1.f) * (y2 - y1 + 1.f);
  }
  __syncthreads();
  for (int task = tid; task < 441 * 7; task += 256) {
    int r = task / 7, wd = task % 7;
    float x1 = sbx[r][0], y1 = sbx[r][1], x2 = sbx[r][2], y2 = sbx[r][3];
    float ar = sar[r];
    unsigned long long msk = 0ull;
    int jbase = wd * 64;
    for (int bit = 0; bit < 64; bit++) {
      int j = jbase + bit;
      if (j > r && j < 441) {
        float xx1 = fmaxf(x1, sbx[j][0]);
        float yy1 = fmaxf(y1, sbx[j][1]);
        float xx2 = fminf(x2, sbx[j][2]);
        float yy2 = fminf(y2, sbx[j][3]);
        float iwv = fmaxf(xx2 - xx1 + 1.f, 0.f);
        float ihv = fmaxf(yy2 - yy1 + 1.f, 0.f);
        float inter = iwv * ihv;
        float iou = inter / (ar + sar[j] - inter);
        if (iou > 0.7f) msk |= (1ull << bit);
      }
    }
    sup[r][wd] = msk;
  }
  __syncthreads();
  if (tid < 64) {
    int wd = (tid < 7) ? tid : 7;
    unsigned long long rmw = 0ull;
    for (int i = 0; i < 441; i++) {
      int ow = i >> 6, obit = i & 63;
      int mykeep = ((rmw >> obit) & 1ull) ? 0 : 1;
      int kept = __shfl(mykeep, ow, 64);
      if (kept && wd < 7) rmw |= sup[i][wd];
    }
    if (wd < 7) {
      unsigned long long k = ~rmw;
      if (wd == 6) k &= (1ull << 57) - 1;   // 441 bits total
      kw[wd] = k;
    }
  }
  __syncthreads();
  for (int r = tid; r < POSTN; r += 256) {
    long oo = ((long)bg * POSTN + r) * 5;
    rois[oo] = (float)bg;
    rois[oo + 1] = 0.f; rois[oo + 2] = 0.f;
    rois[oo + 3] = 0.f; rois[oo + 4] = 0.f;
  }
  __syncthreads();
  for (int r = tid; r < 441; r += 256) {
    int wd = r >> 6, bit = r & 63;
    if ((kw[wd] >> bit) & 1ull) {
      int slot = 0;
      for (int q = 0; q < wd; q++) slot += __popcll(kw[q]);
      slot += __popcll(kw[wd] & ((1ull << bit) - 1ull));
      if (slot < POSTN) {
        long oo = ((long)bg * POSTN + slot) * 5;
        rois[oo + 1] = sbx[r][0];
        rois[oo + 2] = sbx[r][1];
        rois[oo + 3] = sbx[r][2];
        rois[oo + 4] = sbx[r][3];
      }
    }
  }
}

// ---------- final scrub: non-finite f32 -> 0 (safety net) ----------
__global__ __launch_bounds__(256) void scrub_f32(float* __restrict__ o, int n) {
  int i = blockIdx.x * 256 + threadIdx.x;
  if (i >= n) return;
  float v = o[i];
  if (!(v == v) || fabsf(v) > 1e30f) o[i] = 0.f;
}

__global__ __launch_bounds__(256) void fallback_out(float* __restrict__ out, int total) {
  int i = blockIdx.x * 256 + threadIdx.x;
  if (i >= total) return;
  out[i] = 0.f;
}

extern "C" void kernel_launch(void* const* d_in, const int* in_sizes, int n_in,
                              void* d_out, int out_size, void* d_ws, size_t ws_size,
                              hipStream_t stream) {
  const void* base_feat = d_in[0];
  const void* im_info   = d_in[1];
  const void* w1 = d_in[4];
  const void* b1 = d_in[5];
  const void* w2 = d_in[6];
  const void* b2 = d_in[7];
  const void* cw = d_in[8];
  const void* cb = d_in[9];
  const void* bw = d_in[10];
  const void* bb = d_in[11];
  float* out = (float*)d_out;   // reference output dtype = float32

  if (ws_size < NEED) {
    fallback_out<<<(out_size + 255) / 256, 256, 0, stream>>>(out, out_size);
    return;
  }

  char* ws = (char*)d_ws;
  float* XpT  = (float*)(ws + XPT_OFF);    // f32 mode
  u16*   Xp16 = (u16*)(ws + XPT_OFF);      // bf16 mode (11.94 MB)
  u16*   YtL  = (u16*)(ws + YTL_OFF);      // bf16 mode (inside old XpT region)
  float* Yt   = (float*)(ws + YT_OFF);     // f32 mode
  u32*   YtHM = (u32*)(ws + YT_OFF);       // bf16 mode (same bytes)
  float* F    = (float*)(ws + F_OFF);
  float* Part = (float*)(ws + PART_OFF);
  float* Sc   = (float*)(ws + SC_OFF);
  float* Bx   = (float*)(ws + BX_OFF);
  int*   K1   = (int*)(ws + K1_OFF);
  int*   K2   = (int*)(ws + K2_OFF);
  int*   Flag = (int*)(ws + FLAG_OFF);

  detect_dtype<<<1, 256, 0, stream>>>(base_feat, w1, Flag);
  build_koff<<<288, 256, 0, stream>>>(K1, K2);

  for (int c = 0; c < 4; c++) {
    hipMemsetAsync(XpT, 0, 23887872ull, stream);   // Xp halos (covers Xp16 + YtL regions)
    hipMemsetAsync(Yt, 0, 21233664ull, stream);    // Yt spatial borders (f32 or HM plane)
    pad_x<<<12544, 256, 0, stream>>>(base_feat, XpT, Xp16, Flag, c * 8);
    gemm_f32<1><<<784, 256, 0, stream>>>(XpT, w1, b1, Yt, nullptr, K1, Flag);     // f32 mode
    gemm_mf1<<<392, 256, 0, stream>>>(Xp16, w1, b1, YtHM, YtL, K1, Flag);         // bf16 mode
    gemm_f32<2><<<224, 256, 0, stream>>>(Yt, w2, nullptr, nullptr, Part, K2, Flag); // f32 mode
    gemm_mf2<<<224, 256, 0, stream>>>(YtHM, YtL, w2, Part, K2, Flag);             // bf16 mode
    reduce2<<<784, 256, 0, stream>>>(Part, b2, F, Flag, c);
  }

  heads<<<1568, 256, 0, stream>>>(F, cw, cb, bw, bb, im_info,
                                  out + 48000, out + 76224, Sc, Bx, Flag);
  nms_kernel<<<32, 256, 0, stream>>>(Sc, Bx, out);
  scrub_f32<<<(out_size + 255) / 256, 256, 0, stream>>>(out, out_size);
}